// Round 1
// baseline (334.026 us; speedup 1.0000x reference)
//
#include <hip/hip_runtime.h>

#define N_NODES  100000
#define N_EDGES  1600000
#define N_GRAPHS 128
#define DD       64
#define EPSV     1e-5f

// workspace byte offsets (512-aligned)
#define O_DEG   0u         // int[N]
#define O_RS    400384u    // int[N]  row_start (exclusive scan of deg)
#define O_CUR   800768u    // int[N]  fill cursor
#define O_CSR   1201152u   // int[E]  src indices grouped by dst
#define O_PART  7601152u   // int[128] scan partials
#define O_GACC  7601664u   // float[G*D] graph accumulator
// total ~7.45 MB

__global__ __launch_bounds__(256) void hist_k(const int* __restrict__ ei, int* __restrict__ deg) {
  int e = blockIdx.x * 256 + threadIdx.x;
  if (e < N_EDGES) atomicAdd(&deg[ei[N_EDGES + e]], 1);
}

__global__ __launch_bounds__(1024) void scan1_k(const int* __restrict__ deg, int* __restrict__ rs,
                                                int* __restrict__ part) {
  __shared__ int a[1024], b[1024];
  int t = threadIdx.x;
  int i = blockIdx.x * 1024 + t;
  int v = (i < N_NODES) ? deg[i] : 0;
  a[t] = v; __syncthreads();
  int* src = a; int* dst = b;
  for (int off = 1; off < 1024; off <<= 1) {
    int s = src[t];
    if (t >= off) s += src[t - off];
    dst[t] = s; __syncthreads();
    int* tmp = src; src = dst; dst = tmp;
  }
  if (i < N_NODES) rs[i] = src[t] - v;           // exclusive within block
  if (t == 1023) part[blockIdx.x] = src[1023];   // block total
}

__global__ __launch_bounds__(128) void scan2_k(int* part, int n) {
  __shared__ int a[128], b[128];
  int t = threadIdx.x;
  int v = (t < n) ? part[t] : 0;
  a[t] = v; __syncthreads();
  int* src = a; int* dst = b;
  for (int off = 1; off < 128; off <<= 1) {
    int s = src[t];
    if (t >= off) s += src[t - off];
    dst[t] = s; __syncthreads();
    int* tmp = src; src = dst; dst = tmp;
  }
  if (t < n) part[t] = src[t] - v;               // exclusive
}

__global__ __launch_bounds__(256) void scan3_k(int* __restrict__ rs, int* __restrict__ cur,
                                               const int* __restrict__ part) {
  int i = blockIdx.x * 256 + threadIdx.x;
  if (i < N_NODES) {
    int v = rs[i] + part[i >> 10];
    rs[i] = v; cur[i] = v;
  }
}

__global__ __launch_bounds__(256) void fill_k(const int* __restrict__ ei, int* __restrict__ cur,
                                              int* __restrict__ csr) {
  int e = blockIdx.x * 256 + threadIdx.x;
  if (e < N_EDGES) {
    int s = ei[e], d = ei[N_EDGES + e];
    int p = atomicAdd(&cur[d], 1);
    csr[p] = s;
  }
}

// one wave per node (lane = dim): pull-based mean aggregation, h -> d_out node region
__global__ __launch_bounds__(256) void agg_k(const float* __restrict__ x, const int* __restrict__ rs,
                                             const int* __restrict__ deg, const int* __restrict__ csr,
                                             float* __restrict__ h) {
  int wl   = __builtin_amdgcn_readfirstlane(threadIdx.x >> 6);
  int lane = threadIdx.x & 63;
  int node = blockIdx.x * 4 + wl;
  if (node >= N_NODES) return;
  int r0 = rs[node];
  int dg = deg[node];
  float a0 = 0.f, a1 = 0.f, a2 = 0.f, a3 = 0.f;
  int j = 0;
  for (; j + 3 < dg; j += 4) {        // 4 gathers in flight per iteration
    int s0 = csr[r0 + j], s1 = csr[r0 + j + 1], s2 = csr[r0 + j + 2], s3 = csr[r0 + j + 3];
    a0 += x[(size_t)s0 * DD + lane];
    a1 += x[(size_t)s1 * DD + lane];
    a2 += x[(size_t)s2 * DD + lane];
    a3 += x[(size_t)s3 * DD + lane];
  }
  for (; j < dg; ++j) {
    int s = csr[r0 + j];
    a0 += x[(size_t)s * DD + lane];
  }
  float acc = (a0 + a1) + (a2 + a3);
  h[(size_t)node * DD + lane] = acc / fmaxf((float)dg, 1.f);
}

// one wave per 8 nodes (lane = dim): GEMMs via scalar-pipe activations, epilogue + pooling
#define NB 8
__global__ __launch_bounds__(256) void comb_k(const float* __restrict__ x, const float* h,
                                              const float* __restrict__ Wself, const float* __restrict__ Wneigh,
                                              const float* __restrict__ bvec, const float* __restrict__ gamma,
                                              const float* __restrict__ beta, const int* __restrict__ batch,
                                              float* __restrict__ gacc, float* out) {
  int wl   = __builtin_amdgcn_readfirstlane(threadIdx.x >> 6);
  int lane = threadIdx.x & 63;
  int nb   = (blockIdx.x * 4 + wl) * NB;   // 3125*4*8 == 100000 exactly
  float bv  = bvec[lane];
  float gv  = gamma[lane];
  float btv = beta[lane];
  float acc[NB];
#pragma unroll
  for (int n = 0; n < NB; ++n) acc[n] = 0.f;
  for (int k = 0; k < DD; k += 4) {
#pragma unroll
    for (int kk = 0; kk < 4; ++kk) {
      float ws = Wself[(k + kk) * DD + lane];   // L1-hot vector loads
      float wn = Wneigh[(k + kk) * DD + lane];
#pragma unroll
      for (int n = 0; n < NB; ++n) {
        size_t base = (size_t)(nb + n) * DD + (k + kk);   // wave-uniform -> s_load
        acc[n] += x[base] * ws + h[base] * wn;
      }
    }
  }
  int gprev = -1; float pool = 0.f;
#pragma unroll
  for (int n = 0; n < NB; ++n) {
    float tmp = acc[n] + bv;                 // pre-residual node_out (pooled)
    int g = batch[nb + n];                   // sorted -> run-length flush
    if (g != gprev) {
      if (gprev >= 0) atomicAdd(&gacc[gprev * DD + lane], pool);
      pool = 0.f; gprev = g;
    }
    pool += tmp;
    float xv  = x[(size_t)(nb + n) * DD + lane];
    float val = tmp + xv;                    // residual
    float s = val;
    for (int off = 32; off; off >>= 1) s += __shfl_xor(s, off);
    float mu  = s * (1.f / 64.f);
    float dlt = val - mu;
    float ss  = dlt * dlt;
    for (int off = 32; off; off >>= 1) ss += __shfl_xor(ss, off);
    float rstd = rsqrtf(ss * (1.f / 64.f) + EPSV);
    float o = dlt * rstd * gv + btv;
    out[(size_t)(nb + n) * DD + lane] = fmaxf(o, 0.f);   // ReLU(LN)
  }
  if (gprev >= 0) atomicAdd(&gacc[gprev * DD + lane], pool);
}

__global__ __launch_bounds__(256) void graph_k(const float* __restrict__ gacc, const float* __restrict__ gemb,
                                               const float* __restrict__ gamma, const float* __restrict__ beta,
                                               float* __restrict__ out) {
  int lane = threadIdx.x & 63;
  int w = blockIdx.x * 4 + (threadIdx.x >> 6);
  if (w >= N_GRAPHS) return;
  float v = gacc[w * DD + lane] + gemb[w * DD + lane];
  float gv = gamma[lane], btv = beta[lane];
#pragma unroll
  for (int it = 0; it < 2; ++it) {           // LN applied twice (per reference)
    float s = v;
    for (int off = 32; off; off >>= 1) s += __shfl_xor(s, off);
    float mu  = s * (1.f / 64.f);
    float d   = v - mu;
    float ss  = d * d;
    for (int off = 32; off; off >>= 1) ss += __shfl_xor(ss, off);
    v = d * rsqrtf(ss * (1.f / 64.f) + EPSV) * gv + btv;
  }
  out[(size_t)N_NODES * DD + w * DD + lane] = v;
}

extern "C" void kernel_launch(void* const* d_in, const int* in_sizes, int n_in,
                              void* d_out, int out_size, void* d_ws, size_t ws_size,
                              hipStream_t stream) {
  const float* x      = (const float*)d_in[0];
  const int*   ei     = (const int*)d_in[1];
  const int*   batch  = (const int*)d_in[2];
  const float* gemb   = (const float*)d_in[3];
  const float* Wself  = (const float*)d_in[4];
  const float* Wneigh = (const float*)d_in[5];
  const float* bvec   = (const float*)d_in[6];
  const float* gamma  = (const float*)d_in[7];
  const float* beta   = (const float*)d_in[8];

  char* ws = (char*)d_ws;
  int*   deg  = (int*)(ws + O_DEG);
  int*   rs   = (int*)(ws + O_RS);
  int*   cur  = (int*)(ws + O_CUR);
  int*   csr  = (int*)(ws + O_CSR);
  int*   part = (int*)(ws + O_PART);
  float* gacc = (float*)(ws + O_GACC);
  float* outf = (float*)d_out;       // node region doubles as h staging

  hipMemsetAsync(deg, 0, N_NODES * sizeof(int), stream);
  hipMemsetAsync(gacc, 0, N_GRAPHS * DD * sizeof(float), stream);

  hist_k <<<(N_EDGES + 255) / 256, 256, 0, stream>>>(ei, deg);
  scan1_k<<<(N_NODES + 1023) / 1024, 1024, 0, stream>>>(deg, rs, part);
  scan2_k<<<1, 128, 0, stream>>>(part, (N_NODES + 1023) / 1024);
  scan3_k<<<(N_NODES + 255) / 256, 256, 0, stream>>>(rs, cur, part);
  fill_k <<<(N_EDGES + 255) / 256, 256, 0, stream>>>(ei, cur, csr);
  agg_k  <<<(N_NODES + 3) / 4, 256, 0, stream>>>(x, rs, deg, csr, outf);
  comb_k <<<N_NODES / (4 * NB), 256, 0, stream>>>(x, outf, Wself, Wneigh, bvec, gamma, beta,
                                                  batch, gacc, outf);
  graph_k<<<N_GRAPHS / 4, 256, 0, stream>>>(gacc, gemb, gamma, beta, outf);
}